// Round 1
// baseline (652.264 us; speedup 1.0000x reference)
//
#include <hip/hip_runtime.h>
#include <hip/hip_bf16.h>
#include <stdint.h>

#define DIN    2048
#define MROWS  2048
#define LSEQ   512
#define NV     16384
#define DMODEL 1024

typedef __attribute__((ext_vector_type(8))) short bf16x8;
typedef __attribute__((ext_vector_type(4))) float f32x4;

__device__ __forceinline__ uint16_t f2bf(float f) {
  uint32_t u = __builtin_bit_cast(uint32_t, f);
  u += 0x7fffu + ((u >> 16) & 1u);
  return (uint16_t)(u >> 16);
}

__device__ __forceinline__ void gld_lds16(const uint16_t* g, uint16_t* l) {
  __builtin_amdgcn_global_load_lds(
      (const __attribute__((address_space(1))) void*)g,
      (__attribute__((address_space(3))) void*)l,
      16, 0, 0);
}

// C = A(M,K) * B(N,K)^T, fp32 out. 128x128 tile, BK=32, 4 waves, 4x4 frags/wave.
// Optional split-K: gridDim.z slices of kchunk each, slice z writes C + z*M*N.
__global__ __launch_bounds__(256) void gemm_bf16_kernel(
    const uint16_t* __restrict__ A, const uint16_t* __restrict__ B,
    float* __restrict__ C, int M, int N, int K, int kchunk)
{
  __shared__ uint16_t As[128 * 32];
  __shared__ uint16_t Bs[128 * 32];
  const int tid  = threadIdx.x;
  const int wid  = tid >> 6;
  const int lane = tid & 63;
  const int bm = blockIdx.y * 128;
  const int bn = blockIdx.x * 128;
  const int k_beg = blockIdx.z * kchunk;
  float* Cout = C + (size_t)blockIdx.z * M * N;

  const int fr = lane & 15;
  const int fg = lane >> 4;
  const int wm = (wid >> 1) * 64;
  const int wn = (wid & 1) * 64;

  // staging: wave wid loads rows [wid*32, wid*32+32), lane -> row wid*32+c*16+lane/4, k byte (lane&3)*16
  const int srow = wid * 32 + (lane >> 2);
  const int skof = (lane & 3) * 8;
  const uint16_t* Ag = A + (size_t)(bm + srow) * K + skof;
  const uint16_t* Bg = B + (size_t)(bn + srow) * K + skof;
  uint16_t* Al = As + wid * 1024;   // 2KB (1024 elems) per wave: two 1KB chunks
  uint16_t* Bl = Bs + wid * 1024;

  f32x4 acc[4][4] = {};

  for (int k0 = 0; k0 < kchunk; k0 += 32) {
    const int kk = k_beg + k0;
    gld_lds16(Ag + kk, Al);
    gld_lds16(Ag + (size_t)16 * K + kk, Al + 512);
    gld_lds16(Bg + kk, Bl);
    gld_lds16(Bg + (size_t)16 * K + kk, Bl + 512);
    asm volatile("s_waitcnt vmcnt(0)" ::: "memory");
    __syncthreads();
    bf16x8 af[4], bfr[4];
#pragma unroll
    for (int i = 0; i < 4; ++i)
      af[i] = *(const bf16x8*)(As + (wm + i * 16 + fr) * 32 + fg * 8);
#pragma unroll
    for (int j = 0; j < 4; ++j)
      bfr[j] = *(const bf16x8*)(Bs + (wn + j * 16 + fr) * 32 + fg * 8);
#pragma unroll
    for (int i = 0; i < 4; ++i)
#pragma unroll
      for (int j = 0; j < 4; ++j)
        acc[i][j] = __builtin_amdgcn_mfma_f32_16x16x32_bf16(af[i], bfr[j], acc[i][j], 0, 0, 0);
    __syncthreads();
  }

#pragma unroll
  for (int i = 0; i < 4; ++i) {
    const int r0 = bm + wm + i * 16 + fg * 4;
#pragma unroll
    for (int j = 0; j < 4; ++j) {
      const int c0 = bn + wn + j * 16 + fr;
#pragma unroll
      for (int r = 0; r < 4; ++r)
        Cout[(size_t)(r0 + r) * N + c0] = acc[i][j][r];
    }
  }
}

__global__ __launch_bounds__(256) void reduce_slices_kernel(
    const float* __restrict__ in, float* __restrict__ out, int n, int S) {
  const int i = blockIdx.x * 256 + threadIdx.x;
  if (i >= n) return;
  float s = 0.f;
  for (int z = 0; z < S; ++z) s += in[i + (size_t)z * n];
  out[i] = s;
}

__global__ __launch_bounds__(256) void embed_kernel(
    const int* __restrict__ tok, const float* __restrict__ emb, uint16_t* __restrict__ out) {
  const int m = blockIdx.x;
  const int t = tok[m];
  const float4 v = ((const float4*)(emb + (size_t)t * DMODEL))[threadIdx.x];
  ((ushort4*)(out + (size_t)m * DMODEL))[threadIdx.x] =
      make_ushort4(f2bf(v.x), f2bf(v.y), f2bf(v.z), f2bf(v.w));
}

__global__ __launch_bounds__(256) void cvt_bf16_kernel(
    const float* __restrict__ in, uint16_t* __restrict__ out, int n4) {
  const int i = blockIdx.x * 256 + threadIdx.x;
  if (i >= n4) return;
  const float4 v = ((const float4*)in)[i];
  ((ushort4*)out)[i] = make_ushort4(f2bf(v.x), f2bf(v.y), f2bf(v.z), f2bf(v.w));
}

__global__ __launch_bounds__(256) void cvt_pad_kernel(
    const float* __restrict__ in, uint16_t* __restrict__ out, int rows_in, int cols4) {
  const int i = blockIdx.x * 256 + threadIdx.x;   // over rows_out*cols4 (exact grid)
  const int r = i / cols4, c = i % cols4;
  ushort4 o = make_ushort4(0, 0, 0, 0);
  if (r < rows_in) {
    const float4 v = ((const float4*)in)[(size_t)r * cols4 + c];
    o = make_ushort4(f2bf(v.x), f2bf(v.y), f2bf(v.z), f2bf(v.w));
  }
  ((ushort4*)out)[i] = o;
}

// causal depthwise conv (K=4) + bias + silu; reads x = xz[:, 0:2048]
__global__ __launch_bounds__(256) void conv_silu_kernel(
    const float* __restrict__ xz, const float* __restrict__ cw, const float* __restrict__ cb,
    float* __restrict__ xc, uint16_t* __restrict__ xcb)
{
  const int idx = blockIdx.x * 256 + threadIdx.x;  // (m,d)
  const int d = idx & (DIN - 1);
  const int m = idx >> 11;
  const int l = m & (LSEQ - 1);
  float acc = cb[d];
#pragma unroll
  for (int j = 0; j < 4; ++j) {
    const int lj = l - 3 + j;
    if (lj >= 0) acc += cw[d * 4 + j] * xz[(size_t)(m - 3 + j) * 4096 + d];
  }
  const float r = acc / (1.f + __expf(-acc));   // silu
  xc[idx] = r;
  xcb[idx] = f2bf(r);
}

__global__ __launch_bounds__(256) void dt_extract_kernel(
    const float* __restrict__ xdbl, uint16_t* __restrict__ dtb) {
  const int i = blockIdx.x * 256 + threadIdx.x;   // < 2048*64
  const int m = i >> 6, r = i & 63;
  dtb[i] = f2bf(xdbl[(size_t)m * 128 + r]);
}

__global__ __launch_bounds__(256) void softplus_kernel(
    float* __restrict__ dlt, const float* __restrict__ bias) {
  const int i = blockIdx.x * 256 + threadIdx.x;
  const int d = i & (DIN - 1);
  const float u = dlt[i] + bias[d];
  dlt[i] = (u > 20.f) ? u : log1pf(__expf(u));
}

// selective scan: 4 lanes per (b,d) channel, 4 states each; fused y=(ys+x*D)*silu(z) -> bf16
__global__ __launch_bounds__(256) void scan_kernel(
    const float* __restrict__ delta, const float* __restrict__ xc,
    const float* __restrict__ xdbl, const float* __restrict__ xz,
    const float* __restrict__ A_log, const float* __restrict__ Dp,
    uint16_t* __restrict__ yb)
{
  const int gid = blockIdx.x * 256 + threadIdx.x;   // 32768 total
  const int q  = gid & 3;
  const int ch = gid >> 2;
  const int d  = ch & (DIN - 1);
  const int b  = ch >> 11;
  float Arow[4];
#pragma unroll
  for (int n = 0; n < 4; ++n)
    Arow[n] = -expf(A_log[d * 16 + q * 4 + n]);
  const float dpd = Dp[d];
  float h[4] = {0.f, 0.f, 0.f, 0.f};
  for (int l = 0; l < LSEQ; ++l) {
    const int m = b * LSEQ + l;
    const float de = delta[(size_t)m * DIN + d];
    const float xv = xc[(size_t)m * DIN + d];
    const float dx = de * xv;
    const float* bc = xdbl + (size_t)m * 128;
    float yp = 0.f;
#pragma unroll
    for (int n = 0; n < 4; ++n) {
      const float a = __expf(de * Arow[n]);
      h[n] = a * h[n] + dx * bc[64 + q * 4 + n];
      yp += h[n] * bc[80 + q * 4 + n];
    }
    yp += __shfl_xor(yp, 1);
    yp += __shfl_xor(yp, 2);
    if (q == 0) {
      const float z = xz[(size_t)m * 4096 + 2048 + d];
      const float sil = z / (1.f + __expf(-z));
      yb[(size_t)m * DIN + d] = f2bf((yp + xv * dpd) * sil);
    }
  }
}

__global__ __launch_bounds__(256) void pool_kernel(
    const float* __restrict__ h2, float* __restrict__ pooled) {
  const int b = blockIdx.x, t = threadIdx.x;
  const float4* base = (const float4*)(h2 + (size_t)b * LSEQ * DMODEL);
  float sx = 0, sy = 0, sz = 0, sw = 0;
  for (int l = 0; l < LSEQ; ++l) {
    const float4 v = base[l * (DMODEL / 4) + t];
    sx += v.x; sy += v.y; sz += v.z; sw += v.w;
  }
  const float inv = 1.f / LSEQ;
  ((float4*)pooled)[b * (DMODEL / 4) + t] = make_float4(sx * inv, sy * inv, sz * inv, sw * inv);
}

__global__ __launch_bounds__(64) void cls_kernel(
    const float* __restrict__ pooled, const float* __restrict__ w, float* __restrict__ out) {
  const int o = blockIdx.x;            // 0..511  (b*128 + c)
  const int b = o >> 7, c = o & 127;
  const int lane = threadIdx.x;
  const float* p = pooled + b * 1024;
  const float* wr = w + c * 1024;
  float s = 0.f;
  for (int k = lane; k < 1024; k += 64) s += p[k] * wr[k];
#pragma unroll
  for (int off = 32; off > 0; off >>= 1) s += __shfl_down(s, off);
  if (lane == 0) out[o] = s;
}

extern "C" void kernel_launch(void* const* d_in, const int* in_sizes, int n_in,
                              void* d_out, int out_size, void* d_ws, size_t ws_size,
                              hipStream_t stream) {
  const int*   tokens    = (const int*)d_in[0];
  const float* embedding = (const float*)d_in[1];
  const float* in_proj_w = (const float*)d_in[2];
  const float* conv_w    = (const float*)d_in[3];
  const float* conv_b    = (const float*)d_in[4];
  const float* x_proj_w  = (const float*)d_in[5];
  const float* dt_proj_w = (const float*)d_in[6];
  const float* dt_proj_b = (const float*)d_in[7];
  const float* A_log     = (const float*)d_in[8];
  const float* D_param   = (const float*)d_in[9];
  const float* out_prj_w = (const float*)d_in[10];
  const float* recon_w   = (const float*)d_in[11];
  const float* cls_w     = (const float*)d_in[12];

  char* ws = (char*)d_ws;
  const size_t MB = 1024 * 1024;
  uint16_t* h_bf   = (uint16_t*)(ws + 0);        // 4MB   [dead after GEMM1]
  uint16_t* w_in   = (uint16_t*)(ws + 4 * MB);   // 8MB   [dead after GEMM1]
  float*    xz     = (float*)(ws + 12 * MB);     // 32MB  [dead after scan]
  float*    xc_f   = (float*)(ws + 44 * MB);     // 16MB
  uint16_t* xc_b   = (uint16_t*)(ws + 60 * MB);  // 8MB
  uint16_t* wx_bf  = (uint16_t*)(ws + 68 * MB);  // 0.5MB (padded 128x2048)
  float*    xdbl   = (float*)(ws + 69 * MB);     // 1MB   (2048x128)
  uint16_t* dt_bf  = (uint16_t*)(ws + 70 * MB);  // 0.25MB
  uint16_t* wdt_bf = (uint16_t*)(ws + 71 * MB);  // 0.25MB
  float*    delta  = (float*)(ws + 72 * MB);     // 16MB (also split-K scratch)
  uint16_t* y_bf   = (uint16_t*)(ws + 88 * MB);  // 8MB
  uint16_t* h2_bf  = (uint16_t*)(ws + 96 * MB);  // 4MB
  float*    pooled = (float*)(ws + 100 * MB);    // 16KB
  // aliases (lifetime-disjoint)
  uint16_t* wout_bf = h_bf;            // written after GEMM1
  float*    h2_f    = (float*)w_in;    // written after GEMM1
  uint16_t* wrec_bf = (uint16_t*)xz;   // written after scan
  float*    kscr    = delta;           // split-K slices (before/after delta's lifetime)

  const int RECON = MROWS * NV;

  // 1. embedding gather -> bf16
  embed_kernel<<<dim3(MROWS), dim3(256), 0, stream>>>(tokens, embedding, h_bf);
  // 2. in_proj_w -> bf16
  cvt_bf16_kernel<<<dim3(4096), dim3(256), 0, stream>>>(in_proj_w, w_in, 4096 * 1024 / 4);
  // 3. xz = h @ in_proj_w^T   (2048 x 4096, K=1024)
  gemm_bf16_kernel<<<dim3(32, 16, 1), dim3(256), 0, stream>>>(h_bf, w_in, xz, MROWS, 4096, 1024, 1024);
  // 4. remaining weight conversions (wout overwrites h_bf: dead now)
  cvt_bf16_kernel<<<dim3(2048), dim3(256), 0, stream>>>(out_prj_w, wout_bf, 1024 * 2048 / 4);
  cvt_bf16_kernel<<<dim3(128), dim3(256), 0, stream>>>(dt_proj_w, wdt_bf, 2048 * 64 / 4);
  cvt_pad_kernel<<<dim3(256), dim3(256), 0, stream>>>(x_proj_w, wx_bf, 96, 512);
  // 5. causal conv + silu
  conv_silu_kernel<<<dim3(16384), dim3(256), 0, stream>>>(xz, conv_w, conv_b, xc_f, xc_b);
  // 6. x_dbl = x @ x_proj_w^T (split-K x4: 2048 x 128, K=2048)
  gemm_bf16_kernel<<<dim3(1, 16, 4), dim3(256), 0, stream>>>(xc_b, wx_bf, kscr, MROWS, 128, 2048, 512);
  reduce_slices_kernel<<<dim3(1024), dim3(256), 0, stream>>>(kscr, xdbl, MROWS * 128, 4);
  // 7. dt slice -> bf16
  dt_extract_kernel<<<dim3(512), dim3(256), 0, stream>>>(xdbl, dt_bf);
  // 8. delta_raw = dt @ dt_proj_w^T (2048 x 2048, K=64)
  gemm_bf16_kernel<<<dim3(16, 16, 1), dim3(256), 0, stream>>>(dt_bf, wdt_bf, delta, MROWS, DIN, 64, 64);
  // 9. delta = softplus(delta_raw + b)
  softplus_kernel<<<dim3(16384), dim3(256), 0, stream>>>(delta, dt_proj_b);
  // 10. selective scan, fused (ys + x*D)*silu(z) -> y_bf
  scan_kernel<<<dim3(128), dim3(256), 0, stream>>>(delta, xc_f, xdbl, xz, A_log, D_param, y_bf);
  // 11. recon_w -> bf16 (overwrites xz: dead now)
  cvt_bf16_kernel<<<dim3(16384), dim3(256), 0, stream>>>(recon_w, wrec_bf, NV * 1024 / 4);
  // 12. h2 = y @ out_proj_w^T (split-K x2: 2048 x 1024, K=2048)
  gemm_bf16_kernel<<<dim3(8, 16, 2), dim3(256), 0, stream>>>(y_bf, wout_bf, kscr, MROWS, 1024, 2048, 1024);
  reduce_slices_kernel<<<dim3(8192), dim3(256), 0, stream>>>(kscr, h2_f, MROWS * 1024, 2);
  // 13. h2 -> bf16
  cvt_bf16_kernel<<<dim3(2048), dim3(256), 0, stream>>>(h2_f, h2_bf, MROWS * 1024 / 4);
  // 14. recon = h2 @ recon_w^T (2048 x 16384, K=1024) -> d_out
  gemm_bf16_kernel<<<dim3(128, 16, 1), dim3(256), 0, stream>>>(h2_bf, wrec_bf, (float*)d_out, MROWS, NV, 1024, 1024);
  // 15. CLS head
  pool_kernel<<<dim3(4), dim3(256), 0, stream>>>(h2_f, pooled);
  cls_kernel<<<dim3(512), dim3(64), 0, stream>>>(pooled, cls_w, (float*)d_out + RECON);
}

// Round 2
// 386.403 us; speedup vs baseline: 1.6880x; 1.6880x over previous
//
#include <hip/hip_runtime.h>
#include <hip/hip_bf16.h>
#include <stdint.h>

#define DIN    2048
#define MROWS  2048
#define LSEQ   512
#define NV     16384
#define DMODEL 1024
#define NC     8      // scan chunks
#define CL     64     // steps per chunk

typedef __attribute__((ext_vector_type(8))) short bf16x8;
typedef __attribute__((ext_vector_type(4))) float f32x4;

__device__ __forceinline__ uint16_t f2bf(float f) {
  uint32_t u = __builtin_bit_cast(uint32_t, f);
  u += 0x7fffu + ((u >> 16) & 1u);
  return (uint16_t)(u >> 16);
}

__device__ __forceinline__ void gld_lds16(const uint16_t* g, uint16_t* l) {
  __builtin_amdgcn_global_load_lds(
      (const __attribute__((address_space(1))) void*)g,
      (__attribute__((address_space(3))) void*)l,
      16, 0, 0);
}

// C = A(M,K) * B(N,K)^T, fp32 out. 128x128 tile, BK=32, 4 waves, 4x4 frags/wave.
// Optional split-K: gridDim.z slices of kchunk each, slice z writes C + z*M*N.
__global__ __launch_bounds__(256) void gemm_bf16_kernel(
    const uint16_t* __restrict__ A, const uint16_t* __restrict__ B,
    float* __restrict__ C, int M, int N, int K, int kchunk)
{
  __shared__ uint16_t As[128 * 32];
  __shared__ uint16_t Bs[128 * 32];
  const int tid  = threadIdx.x;
  const int wid  = tid >> 6;
  const int lane = tid & 63;
  const int bm = blockIdx.y * 128;
  const int bn = blockIdx.x * 128;
  const int k_beg = blockIdx.z * kchunk;
  float* Cout = C + (size_t)blockIdx.z * M * N;

  const int fr = lane & 15;
  const int fg = lane >> 4;
  const int wm = (wid >> 1) * 64;
  const int wn = (wid & 1) * 64;

  const int srow = wid * 32 + (lane >> 2);
  const int skof = (lane & 3) * 8;
  const uint16_t* Ag = A + (size_t)(bm + srow) * K + skof;
  const uint16_t* Bg = B + (size_t)(bn + srow) * K + skof;
  uint16_t* Al = As + wid * 1024;
  uint16_t* Bl = Bs + wid * 1024;

  f32x4 acc[4][4] = {};

  for (int k0 = 0; k0 < kchunk; k0 += 32) {
    const int kk = k_beg + k0;
    gld_lds16(Ag + kk, Al);
    gld_lds16(Ag + (size_t)16 * K + kk, Al + 512);
    gld_lds16(Bg + kk, Bl);
    gld_lds16(Bg + (size_t)16 * K + kk, Bl + 512);
    asm volatile("s_waitcnt vmcnt(0)" ::: "memory");
    __syncthreads();
    bf16x8 af[4], bfr[4];
#pragma unroll
    for (int i = 0; i < 4; ++i)
      af[i] = *(const bf16x8*)(As + (wm + i * 16 + fr) * 32 + fg * 8);
#pragma unroll
    for (int j = 0; j < 4; ++j)
      bfr[j] = *(const bf16x8*)(Bs + (wn + j * 16 + fr) * 32 + fg * 8);
#pragma unroll
    for (int i = 0; i < 4; ++i)
#pragma unroll
      for (int j = 0; j < 4; ++j)
        acc[i][j] = __builtin_amdgcn_mfma_f32_16x16x32_bf16(af[i], bfr[j], acc[i][j], 0, 0, 0);
    __syncthreads();
  }

#pragma unroll
  for (int i = 0; i < 4; ++i) {
    const int r0 = bm + wm + i * 16 + fg * 4;
#pragma unroll
    for (int j = 0; j < 4; ++j) {
      const int c0 = bn + wn + j * 16 + fr;
#pragma unroll
      for (int r = 0; r < 4; ++r)
        Cout[(size_t)(r0 + r) * N + c0] = acc[i][j][r];
    }
  }
}

__global__ __launch_bounds__(256) void reduce_slices_kernel(
    const float* __restrict__ in, float* __restrict__ out, int n, int S) {
  const int i = blockIdx.x * 256 + threadIdx.x;
  if (i >= n) return;
  float s = 0.f;
  for (int z = 0; z < S; ++z) s += in[i + (size_t)z * n];
  out[i] = s;
}

__global__ __launch_bounds__(256) void embed_kernel(
    const int* __restrict__ tok, const float* __restrict__ emb, uint16_t* __restrict__ out) {
  const int m = blockIdx.x;
  const int t = tok[m];
  const float4 v = ((const float4*)(emb + (size_t)t * DMODEL))[threadIdx.x];
  ((ushort4*)(out + (size_t)m * DMODEL))[threadIdx.x] =
      make_ushort4(f2bf(v.x), f2bf(v.y), f2bf(v.z), f2bf(v.w));
}

__global__ __launch_bounds__(256) void cvt_bf16_kernel(
    const float* __restrict__ in, uint16_t* __restrict__ out, int n4) {
  const int i = blockIdx.x * 256 + threadIdx.x;
  if (i >= n4) return;
  const float4 v = ((const float4*)in)[i];
  ((ushort4*)out)[i] = make_ushort4(f2bf(v.x), f2bf(v.y), f2bf(v.z), f2bf(v.w));
}

__global__ __launch_bounds__(256) void cvt_pad_kernel(
    const float* __restrict__ in, uint16_t* __restrict__ out, int rows_in, int cols4) {
  const int i = blockIdx.x * 256 + threadIdx.x;
  const int r = i / cols4, c = i % cols4;
  ushort4 o = make_ushort4(0, 0, 0, 0);
  if (r < rows_in) {
    const float4 v = ((const float4*)in)[(size_t)r * cols4 + c];
    o = make_ushort4(f2bf(v.x), f2bf(v.y), f2bf(v.z), f2bf(v.w));
  }
  ((ushort4*)out)[i] = o;
}

__global__ __launch_bounds__(256) void conv_silu_kernel(
    const float* __restrict__ xz, const float* __restrict__ cw, const float* __restrict__ cb,
    float* __restrict__ xc, uint16_t* __restrict__ xcb)
{
  const int idx = blockIdx.x * 256 + threadIdx.x;
  const int d = idx & (DIN - 1);
  const int m = idx >> 11;
  const int l = m & (LSEQ - 1);
  float acc = cb[d];
#pragma unroll
  for (int j = 0; j < 4; ++j) {
    const int lj = l - 3 + j;
    if (lj >= 0) acc += cw[d * 4 + j] * xz[(size_t)(m - 3 + j) * 4096 + d];
  }
  const float r = acc / (1.f + __expf(-acc));
  xc[idx] = r;
  xcb[idx] = f2bf(r);
}

__global__ __launch_bounds__(256) void dt_extract_kernel(
    const float* __restrict__ xdbl, uint16_t* __restrict__ dtb) {
  const int i = blockIdx.x * 256 + threadIdx.x;
  const int m = i >> 6, r = i & 63;
  dtb[i] = f2bf(xdbl[(size_t)m * 128 + r]);
}

__global__ __launch_bounds__(256) void softplus_kernel(
    float* __restrict__ dlt, const float* __restrict__ bias) {
  const int i = blockIdx.x * 256 + threadIdx.x;
  const int d = i & (DIN - 1);
  const float u = dlt[i] + bias[d];
  dlt[i] = (u > 20.f) ? u : log1pf(__expf(u));
}

// ---- chunked selective scan ----
// Pass A: per-chunk composed transform. thread = (d_idx, q); q handles n = q*4..q*4+3.
// P = prod(a), Q: Q <- a*Q + dx*B  (recurrence with h0 = 0)
__global__ __launch_bounds__(256) void scan_partial_kernel(
    const float* __restrict__ delta, const float* __restrict__ xc,
    const float* __restrict__ xdbl, const float* __restrict__ A_log,
    float* __restrict__ Pb, float* __restrict__ Qb)
{
  const int q = threadIdx.x & 3;
  const int d_idx = threadIdx.x >> 2;
  const int c = blockIdx.x;            // chunk
  const int d = blockIdx.y * 64 + d_idx;
  const int b = blockIdx.z;
  float Arow[4];
#pragma unroll
  for (int n = 0; n < 4; ++n)
    Arow[n] = -expf(A_log[d * 16 + q * 4 + n]);
  float P[4] = {1.f, 1.f, 1.f, 1.f};
  float Q[4] = {0.f, 0.f, 0.f, 0.f};
  const int l0 = c * CL;
#pragma unroll 4
  for (int li = 0; li < CL; ++li) {
    const int m = b * LSEQ + l0 + li;
    const float de = delta[(size_t)m * DIN + d];
    const float xv = xc[(size_t)m * DIN + d];
    const float dx = de * xv;
    const float4 Bv = *(const float4*)(xdbl + (size_t)m * 128 + 64 + q * 4);
    const float bv[4] = {Bv.x, Bv.y, Bv.z, Bv.w};
#pragma unroll
    for (int n = 0; n < 4; ++n) {
      const float a = __expf(de * Arow[n]);
      P[n] *= a;
      Q[n] = a * Q[n] + dx * bv[n];
    }
  }
  const size_t o = ((size_t)(b * NC + c) * DIN + d) * 16 + q * 4;
  *(float4*)(Pb + o) = make_float4(P[0], P[1], P[2], P[3]);
  *(float4*)(Qb + o) = make_float4(Q[0], Q[1], Q[2], Q[3]);
}

// Pass B: exclusive scan over chunk transforms -> h_init per chunk.
__global__ __launch_bounds__(256) void scan_bounds_kernel(
    const float* __restrict__ Pb, const float* __restrict__ Qb, float* __restrict__ Hi)
{
  const int i = blockIdx.x * 256 + threadIdx.x;   // 131072 = 4*2048*16
  const int b = i >> 15;
  const int r = i & 32767;
  float h = 0.f;
#pragma unroll
  for (int c = 0; c < NC; ++c) {
    const size_t o = ((size_t)(b * NC + c) << 15) + r;
    Hi[o] = h;
    h = Pb[o] * h + Qb[o];
  }
}

// Pass C: replay chunk from boundary state; fused (y + x*D)*silu(z) -> bf16.
__global__ __launch_bounds__(256) void scan_final_kernel(
    const float* __restrict__ delta, const float* __restrict__ xc,
    const float* __restrict__ xdbl, const float* __restrict__ xz,
    const float* __restrict__ A_log, const float* __restrict__ Dp,
    const float* __restrict__ Hi, uint16_t* __restrict__ yb)
{
  const int q = threadIdx.x & 3;
  const int d_idx = threadIdx.x >> 2;
  const int c = blockIdx.x;
  const int d = blockIdx.y * 64 + d_idx;
  const int b = blockIdx.z;
  float Arow[4];
#pragma unroll
  for (int n = 0; n < 4; ++n)
    Arow[n] = -expf(A_log[d * 16 + q * 4 + n]);
  const float dpd = Dp[d];
  const size_t o = ((size_t)(b * NC + c) * DIN + d) * 16 + q * 4;
  const float4 Hv = *(const float4*)(Hi + o);
  float h[4] = {Hv.x, Hv.y, Hv.z, Hv.w};
  const int l0 = c * CL;
#pragma unroll 2
  for (int li = 0; li < CL; ++li) {
    const int m = b * LSEQ + l0 + li;
    const float de = delta[(size_t)m * DIN + d];
    const float xv = xc[(size_t)m * DIN + d];
    const float dx = de * xv;
    const float4 Bv = *(const float4*)(xdbl + (size_t)m * 128 + 64 + q * 4);
    const float4 Cv = *(const float4*)(xdbl + (size_t)m * 128 + 80 + q * 4);
    const float bv[4] = {Bv.x, Bv.y, Bv.z, Bv.w};
    const float cv[4] = {Cv.x, Cv.y, Cv.z, Cv.w};
    float yp = 0.f;
#pragma unroll
    for (int n = 0; n < 4; ++n) {
      const float a = __expf(de * Arow[n]);
      h[n] = a * h[n] + dx * bv[n];
      yp += h[n] * cv[n];
    }
    yp += __shfl_xor(yp, 1);
    yp += __shfl_xor(yp, 2);
    if (q == 0) {
      const float z = xz[(size_t)m * 4096 + 2048 + d];
      const float sil = z / (1.f + __expf(-z));
      yb[(size_t)m * DIN + d] = f2bf((yp + xv * dpd) * sil);
    }
  }
}

__global__ __launch_bounds__(256) void pool_kernel(
    const float* __restrict__ h2, float* __restrict__ pooled) {
  const int b = blockIdx.x, t = threadIdx.x;
  const float4* base = (const float4*)(h2 + (size_t)b * LSEQ * DMODEL);
  float sx = 0, sy = 0, sz = 0, sw = 0;
  for (int l = 0; l < LSEQ; ++l) {
    const float4 v = base[l * (DMODEL / 4) + t];
    sx += v.x; sy += v.y; sz += v.z; sw += v.w;
  }
  const float inv = 1.f / LSEQ;
  ((float4*)pooled)[b * (DMODEL / 4) + t] = make_float4(sx * inv, sy * inv, sz * inv, sw * inv);
}

__global__ __launch_bounds__(64) void cls_kernel(
    const float* __restrict__ pooled, const float* __restrict__ w, float* __restrict__ out) {
  const int o = blockIdx.x;
  const int b = o >> 7, c = o & 127;
  const int lane = threadIdx.x;
  const float* p = pooled + b * 1024;
  const float* wr = w + c * 1024;
  float s = 0.f;
  for (int k = lane; k < 1024; k += 64) s += p[k] * wr[k];
#pragma unroll
  for (int off = 32; off > 0; off >>= 1) s += __shfl_down(s, off);
  if (lane == 0) out[o] = s;
}

extern "C" void kernel_launch(void* const* d_in, const int* in_sizes, int n_in,
                              void* d_out, int out_size, void* d_ws, size_t ws_size,
                              hipStream_t stream) {
  const int*   tokens    = (const int*)d_in[0];
  const float* embedding = (const float*)d_in[1];
  const float* in_proj_w = (const float*)d_in[2];
  const float* conv_w    = (const float*)d_in[3];
  const float* conv_b    = (const float*)d_in[4];
  const float* x_proj_w  = (const float*)d_in[5];
  const float* dt_proj_w = (const float*)d_in[6];
  const float* dt_proj_b = (const float*)d_in[7];
  const float* A_log     = (const float*)d_in[8];
  const float* D_param   = (const float*)d_in[9];
  const float* out_prj_w = (const float*)d_in[10];
  const float* recon_w   = (const float*)d_in[11];
  const float* cls_w     = (const float*)d_in[12];

  char* ws = (char*)d_ws;
  const size_t MB = 1024 * 1024;
  uint16_t* h_bf   = (uint16_t*)(ws + 0);        // 4MB
  uint16_t* w_in   = (uint16_t*)(ws + 4 * MB);   // 8MB  [dead after GEMM1]
  float*    xz     = (float*)(ws + 12 * MB);     // 32MB [dead after scan C]
  float*    xc_f   = (float*)(ws + 44 * MB);     // 16MB
  uint16_t* xc_b   = (uint16_t*)(ws + 60 * MB);  // 8MB  [dead after x_proj GEMM]
  uint16_t* wx_bf  = (uint16_t*)(ws + 68 * MB);  // 0.5MB
  float*    xdbl   = (float*)(ws + 69 * MB);     // 1MB
  uint16_t* dt_bf  = (uint16_t*)(ws + 70 * MB);  // 0.25MB
  uint16_t* wdt_bf = (uint16_t*)(ws + 71 * MB);  // 0.25MB
  float*    delta  = (float*)(ws + 72 * MB);     // 16MB (also split-K scratch)
  uint16_t* y_bf   = (uint16_t*)(ws + 88 * MB);  // 8MB
  uint16_t* h2_bf  = (uint16_t*)(ws + 96 * MB);  // 4MB
  float*    pooled = (float*)(ws + 100 * MB);    // 16KB
  // aliases (lifetime-disjoint)
  uint16_t* wout_bf = h_bf;
  float*    h2_f    = (float*)w_in;              // written at step 12 (after scan)
  uint16_t* wrec_bf = (uint16_t*)xz;             // written after scan
  float*    kscr    = delta;
  float*    Pbuf    = (float*)(ws + 60 * MB);    // 4MB (xc_b region, dead)
  float*    Qbuf    = (float*)(ws + 64 * MB);    // 4MB
  float*    Hinit   = (float*)(ws + 4 * MB);     // 4MB (w_in region, dead)

  const int RECON = MROWS * NV;

  embed_kernel<<<dim3(MROWS), dim3(256), 0, stream>>>(tokens, embedding, h_bf);
  cvt_bf16_kernel<<<dim3(4096), dim3(256), 0, stream>>>(in_proj_w, w_in, 4096 * 1024 / 4);
  gemm_bf16_kernel<<<dim3(32, 16, 1), dim3(256), 0, stream>>>(h_bf, w_in, xz, MROWS, 4096, 1024, 1024);
  cvt_bf16_kernel<<<dim3(2048), dim3(256), 0, stream>>>(out_prj_w, wout_bf, 1024 * 2048 / 4);
  cvt_bf16_kernel<<<dim3(128), dim3(256), 0, stream>>>(dt_proj_w, wdt_bf, 2048 * 64 / 4);
  cvt_pad_kernel<<<dim3(256), dim3(256), 0, stream>>>(x_proj_w, wx_bf, 96, 512);
  conv_silu_kernel<<<dim3(16384), dim3(256), 0, stream>>>(xz, conv_w, conv_b, xc_f, xc_b);
  gemm_bf16_kernel<<<dim3(1, 16, 4), dim3(256), 0, stream>>>(xc_b, wx_bf, kscr, MROWS, 128, 2048, 512);
  reduce_slices_kernel<<<dim3(1024), dim3(256), 0, stream>>>(kscr, xdbl, MROWS * 128, 4);
  dt_extract_kernel<<<dim3(512), dim3(256), 0, stream>>>(xdbl, dt_bf);
  gemm_bf16_kernel<<<dim3(16, 16, 1), dim3(256), 0, stream>>>(dt_bf, wdt_bf, delta, MROWS, DIN, 64, 64);
  softplus_kernel<<<dim3(16384), dim3(256), 0, stream>>>(delta, dt_proj_b);
  // chunked selective scan (A: partials, B: boundaries, C: replay + epilogue)
  scan_partial_kernel<<<dim3(NC, 32, 4), dim3(256), 0, stream>>>(delta, xc_f, xdbl, A_log, Pbuf, Qbuf);
  scan_bounds_kernel<<<dim3(512), dim3(256), 0, stream>>>(Pbuf, Qbuf, Hinit);
  scan_final_kernel<<<dim3(NC, 32, 4), dim3(256), 0, stream>>>(delta, xc_f, xdbl, xz, A_log, D_param, Hinit, y_bf);
  // recon_w -> bf16 (xz dead now)
  cvt_bf16_kernel<<<dim3(16384), dim3(256), 0, stream>>>(recon_w, wrec_bf, NV * 1024 / 4);
  gemm_bf16_kernel<<<dim3(8, 16, 2), dim3(256), 0, stream>>>(y_bf, wout_bf, kscr, MROWS, 1024, 2048, 1024);
  reduce_slices_kernel<<<dim3(8192), dim3(256), 0, stream>>>(kscr, h2_f, MROWS * 1024, 2);
  cvt_bf16_kernel<<<dim3(2048), dim3(256), 0, stream>>>(h2_f, h2_bf, MROWS * 1024 / 4);
  gemm_bf16_kernel<<<dim3(128, 16, 1), dim3(256), 0, stream>>>(h2_bf, wrec_bf, (float*)d_out, MROWS, NV, 1024, 1024);
  pool_kernel<<<dim3(4), dim3(256), 0, stream>>>(h2_f, pooled);
  cls_kernel<<<dim3(512), dim3(64), 0, stream>>>(pooled, cls_w, (float*)d_out + RECON);
}

// Round 3
// 382.862 us; speedup vs baseline: 1.7037x; 1.0092x over previous
//
#include <hip/hip_runtime.h>
#include <hip/hip_bf16.h>
#include <stdint.h>

#define DIN    2048
#define MROWS  2048
#define LSEQ   512
#define NV     16384
#define DMODEL 1024
#define NC     8      // scan chunks
#define CL     64     // steps per chunk

typedef __attribute__((ext_vector_type(8))) short bf16x8;
typedef __attribute__((ext_vector_type(4))) float f32x4;

__device__ __forceinline__ uint16_t f2bf(float f) {
  uint32_t u = __builtin_bit_cast(uint32_t, f);
  u += 0x7fffu + ((u >> 16) & 1u);
  return (uint16_t)(u >> 16);
}

__device__ __forceinline__ void gld_lds16(const uint16_t* g, uint16_t* l) {
  __builtin_amdgcn_global_load_lds(
      (const __attribute__((address_space(1))) void*)g,
      (__attribute__((address_space(3))) void*)l,
      16, 0, 0);
}

// ---------------------------------------------------------------------------
// 256x256 tile, BK=32, 8 waves (2M x 4N), 4-slot LDS (128KB) counted-vmcnt
// pipeline, XOR-swizzled LDS (conflict-free ds_read_b128), XCD-aware swizzle.
// C = A(M,K) * B(N,K)^T fp32. Requires M%256==0, N%256==0, K%32==0, K>=128,
// grid = (M/256)*(N/256) with grid%8==0.
// ---------------------------------------------------------------------------
__global__ __launch_bounds__(512, 2) void gemm256_bf16_kernel(
    const uint16_t* __restrict__ A, const uint16_t* __restrict__ B,
    float* __restrict__ C, int M, int N, int K)
{
  __shared__ uint16_t lds[4 * 16384];   // 4 slots x (A 16KB | B 16KB)
  const int tid = threadIdx.x;
  const int w   = tid >> 6;
  const int l   = tid & 63;

  // XCD swizzle: consecutive swz within an XCD share a bn strip (B L2-resident)
  const int nwg = gridDim.x;
  const int cpx = nwg >> 3;
  const int swz = (blockIdx.x & 7) * cpx + (blockIdx.x >> 3);
  const int nmy = M >> 8;
  const int bm  = (swz % nmy) << 8;
  const int bn  = (swz / nmy) << 8;

  const int fr = l & 15;
  const int fg = l >> 4;
  const int wr = w >> 2;     // 0..1
  const int wc = w & 3;      // 0..3

  // ---- staging constants (source pre-swizzled, LDS dest linear) ----
  // chunk c=(w*2+i) covers rows c*16..c*16+15; lane l -> row c*16+(l>>2),
  // phys c16 = l&3 holds logical c16 = (l&3) ^ ((l>>3)&3)
  const int srow = l >> 2;
  const int kof  = (((l & 3) ^ ((l >> 3) & 3)) << 3);
  const int ar0  = (w * 2 + 0) * 16 + srow;
  const int ar1  = (w * 2 + 1) * 16 + srow;
  const uint16_t* Ag0 = A + (size_t)(bm + ar0) * K + kof;
  const uint16_t* Ag1 = A + (size_t)(bm + ar1) * K + kof;
  const uint16_t* Bg0 = B + (size_t)(bn + ar0) * K + kof;
  const uint16_t* Bg1 = B + (size_t)(bn + ar1) * K + kof;
  const int lA0 = (w * 2 + 0) * 512;          // elem offsets, wave-uniform
  const int lA1 = (w * 2 + 1) * 512;
  const int lB0 = 8192 + (w * 2 + 0) * 512;
  const int lB1 = 8192 + (w * 2 + 1) * 512;

  // ---- ds_read offsets (swizzled): elem = row*32 + (fg ^ ((row>>1)&3))*8,
  // row&7 bits come only from fr, so xor term is per-thread constant
  const int axr  = ((fg ^ ((fr >> 1) & 3)) << 3);
  const int aoff = (wr * 128 + fr) * 32 + axr;          // + mi*512
  const int boff = 8192 + (wc * 64 + fr) * 32 + axr;    // + ni*512

  f32x4 acc[8][4] = {};
  const int NT = K >> 5;

  auto stage = [&](int t) {
    const int sb = (t & 3) << 14;
    const int k0 = t << 5;
    gld_lds16(Ag0 + k0, lds + sb + lA0);
    gld_lds16(Ag1 + k0, lds + sb + lA1);
    gld_lds16(Bg0 + k0, lds + sb + lB0);
    gld_lds16(Bg1 + k0, lds + sb + lB1);
  };
  auto compute_tile = [&](int sb) {
    bf16x8 af[8], bfr[4];
#pragma unroll
    for (int mi = 0; mi < 8; ++mi)
      af[mi] = *(const bf16x8*)(lds + sb + aoff + mi * 512);
#pragma unroll
    for (int ni = 0; ni < 4; ++ni)
      bfr[ni] = *(const bf16x8*)(lds + sb + boff + ni * 512);
    __builtin_amdgcn_s_setprio(1);
#pragma unroll
    for (int mi = 0; mi < 8; ++mi)
#pragma unroll
      for (int ni = 0; ni < 4; ++ni)
        acc[mi][ni] = __builtin_amdgcn_mfma_f32_16x16x32_bf16(af[mi], bfr[ni], acc[mi][ni], 0, 0, 0);
    __builtin_amdgcn_s_setprio(0);
  };

  // prologue: tiles 0..2 in flight (12 loads), wait tile 0 (leave 8)
  stage(0); stage(1); stage(2);
  asm volatile("s_waitcnt vmcnt(8)" ::: "memory");
  __builtin_amdgcn_s_barrier();

  for (int t = 0; t < NT - 3; ++t) {
    stage(t + 3);                       // slot (t+3)&3: consumed at iter t-1
    compute_tile((t & 3) << 14);
    asm volatile("s_waitcnt vmcnt(8)" ::: "memory");   // tile t+1 landed
    __builtin_amdgcn_s_barrier();
  }
  compute_tile(((NT - 3) & 3) << 14);
  asm volatile("s_waitcnt vmcnt(4)" ::: "memory");
  __builtin_amdgcn_s_barrier();
  compute_tile(((NT - 2) & 3) << 14);
  asm volatile("s_waitcnt vmcnt(0)" ::: "memory");
  __builtin_amdgcn_s_barrier();
  compute_tile(((NT - 1) & 3) << 14);

#pragma unroll
  for (int mi = 0; mi < 8; ++mi) {
    const int r0 = bm + wr * 128 + mi * 16 + fg * 4;
#pragma unroll
    for (int ni = 0; ni < 4; ++ni) {
      const int c0 = bn + wc * 64 + ni * 16 + fr;
#pragma unroll
      for (int r = 0; r < 4; ++r)
        C[(size_t)(r0 + r) * N + c0] = acc[mi][ni][r];
    }
  }
}

// ---- 128x128 legacy kernel (small GEMMs: K=64 / N=128 split-K) ----
__global__ __launch_bounds__(256) void gemm_bf16_kernel(
    const uint16_t* __restrict__ A, const uint16_t* __restrict__ B,
    float* __restrict__ C, int M, int N, int K, int kchunk)
{
  __shared__ uint16_t As[128 * 32];
  __shared__ uint16_t Bs[128 * 32];
  const int tid  = threadIdx.x;
  const int wid  = tid >> 6;
  const int lane = tid & 63;
  const int bm = blockIdx.y * 128;
  const int bn = blockIdx.x * 128;
  const int k_beg = blockIdx.z * kchunk;
  float* Cout = C + (size_t)blockIdx.z * M * N;

  const int fr = lane & 15;
  const int fg = lane >> 4;
  const int wm = (wid >> 1) * 64;
  const int wn = (wid & 1) * 64;

  const int srow = wid * 32 + (lane >> 2);
  const int skof = (lane & 3) * 8;
  const uint16_t* Ag = A + (size_t)(bm + srow) * K + skof;
  const uint16_t* Bg = B + (size_t)(bn + srow) * K + skof;
  uint16_t* Al = As + wid * 1024;
  uint16_t* Bl = Bs + wid * 1024;

  f32x4 acc[4][4] = {};

  for (int k0 = 0; k0 < kchunk; k0 += 32) {
    const int kk = k_beg + k0;
    gld_lds16(Ag + kk, Al);
    gld_lds16(Ag + (size_t)16 * K + kk, Al + 512);
    gld_lds16(Bg + kk, Bl);
    gld_lds16(Bg + (size_t)16 * K + kk, Bl + 512);
    asm volatile("s_waitcnt vmcnt(0)" ::: "memory");
    __syncthreads();
    bf16x8 af[4], bfr[4];
#pragma unroll
    for (int i = 0; i < 4; ++i)
      af[i] = *(const bf16x8*)(As + (wm + i * 16 + fr) * 32 + fg * 8);
#pragma unroll
    for (int j = 0; j < 4; ++j)
      bfr[j] = *(const bf16x8*)(Bs + (wn + j * 16 + fr) * 32 + fg * 8);
#pragma unroll
    for (int i = 0; i < 4; ++i)
#pragma unroll
      for (int j = 0; j < 4; ++j)
        acc[i][j] = __builtin_amdgcn_mfma_f32_16x16x32_bf16(af[i], bfr[j], acc[i][j], 0, 0, 0);
    __syncthreads();
  }

#pragma unroll
  for (int i = 0; i < 4; ++i) {
    const int r0 = bm + wm + i * 16 + fg * 4;
#pragma unroll
    for (int j = 0; j < 4; ++j) {
      const int c0 = bn + wn + j * 16 + fr;
#pragma unroll
      for (int r = 0; r < 4; ++r)
        Cout[(size_t)(r0 + r) * N + c0] = acc[i][j][r];
    }
  }
}

__global__ __launch_bounds__(256) void reduce_slices_kernel(
    const float* __restrict__ in, float* __restrict__ out, int n, int S) {
  const int i = blockIdx.x * 256 + threadIdx.x;
  if (i >= n) return;
  float s = 0.f;
  for (int z = 0; z < S; ++z) s += in[i + (size_t)z * n];
  out[i] = s;
}

__global__ __launch_bounds__(256) void embed_kernel(
    const int* __restrict__ tok, const float* __restrict__ emb, uint16_t* __restrict__ out) {
  const int m = blockIdx.x;
  const int t = tok[m];
  const float4 v = ((const float4*)(emb + (size_t)t * DMODEL))[threadIdx.x];
  ((ushort4*)(out + (size_t)m * DMODEL))[threadIdx.x] =
      make_ushort4(f2bf(v.x), f2bf(v.y), f2bf(v.z), f2bf(v.w));
}

__global__ __launch_bounds__(256) void cvt_bf16_kernel(
    const float* __restrict__ in, uint16_t* __restrict__ out, int n4) {
  const int i = blockIdx.x * 256 + threadIdx.x;
  if (i >= n4) return;
  const float4 v = ((const float4*)in)[i];
  ((ushort4*)out)[i] = make_ushort4(f2bf(v.x), f2bf(v.y), f2bf(v.z), f2bf(v.w));
}

__global__ __launch_bounds__(256) void cvt_pad_kernel(
    const float* __restrict__ in, uint16_t* __restrict__ out, int rows_in, int cols4) {
  const int i = blockIdx.x * 256 + threadIdx.x;
  const int r = i / cols4, c = i % cols4;
  ushort4 o = make_ushort4(0, 0, 0, 0);
  if (r < rows_in) {
    const float4 v = ((const float4*)in)[(size_t)r * cols4 + c];
    o = make_ushort4(f2bf(v.x), f2bf(v.y), f2bf(v.z), f2bf(v.w));
  }
  ((ushort4*)out)[i] = o;
}

__global__ __launch_bounds__(256) void conv_silu_kernel(
    const float* __restrict__ xz, const float* __restrict__ cw, const float* __restrict__ cb,
    float* __restrict__ xc, uint16_t* __restrict__ xcb)
{
  const int idx = blockIdx.x * 256 + threadIdx.x;
  const int d = idx & (DIN - 1);
  const int m = idx >> 11;
  const int l = m & (LSEQ - 1);
  float acc = cb[d];
#pragma unroll
  for (int j = 0; j < 4; ++j) {
    const int lj = l - 3 + j;
    if (lj >= 0) acc += cw[d * 4 + j] * xz[(size_t)(m - 3 + j) * 4096 + d];
  }
  const float r = acc / (1.f + __expf(-acc));
  xc[idx] = r;
  xcb[idx] = f2bf(r);
}

__global__ __launch_bounds__(256) void dt_extract_kernel(
    const float* __restrict__ xdbl, uint16_t* __restrict__ dtb) {
  const int i = blockIdx.x * 256 + threadIdx.x;
  const int m = i >> 6, r = i & 63;
  dtb[i] = f2bf(xdbl[(size_t)m * 128 + r]);
}

__global__ __launch_bounds__(256) void softplus_kernel(
    float* __restrict__ dlt, const float* __restrict__ bias) {
  const int i = blockIdx.x * 256 + threadIdx.x;
  const int d = i & (DIN - 1);
  const float u = dlt[i] + bias[d];
  dlt[i] = (u > 20.f) ? u : log1pf(__expf(u));
}

__global__ __launch_bounds__(256) void scan_partial_kernel(
    const float* __restrict__ delta, const float* __restrict__ xc,
    const float* __restrict__ xdbl, const float* __restrict__ A_log,
    float* __restrict__ Pb, float* __restrict__ Qb)
{
  const int q = threadIdx.x & 3;
  const int d_idx = threadIdx.x >> 2;
  const int c = blockIdx.x;
  const int d = blockIdx.y * 64 + d_idx;
  const int b = blockIdx.z;
  float Arow[4];
#pragma unroll
  for (int n = 0; n < 4; ++n)
    Arow[n] = -expf(A_log[d * 16 + q * 4 + n]);
  float P[4] = {1.f, 1.f, 1.f, 1.f};
  float Q[4] = {0.f, 0.f, 0.f, 0.f};
  const int l0 = c * CL;
#pragma unroll 4
  for (int li = 0; li < CL; ++li) {
    const int m = b * LSEQ + l0 + li;
    const float de = delta[(size_t)m * DIN + d];
    const float xv = xc[(size_t)m * DIN + d];
    const float dx = de * xv;
    const float4 Bv = *(const float4*)(xdbl + (size_t)m * 128 + 64 + q * 4);
    const float bv[4] = {Bv.x, Bv.y, Bv.z, Bv.w};
#pragma unroll
    for (int n = 0; n < 4; ++n) {
      const float a = __expf(de * Arow[n]);
      P[n] *= a;
      Q[n] = a * Q[n] + dx * bv[n];
    }
  }
  const size_t o = ((size_t)(b * NC + c) * DIN + d) * 16 + q * 4;
  *(float4*)(Pb + o) = make_float4(P[0], P[1], P[2], P[3]);
  *(float4*)(Qb + o) = make_float4(Q[0], Q[1], Q[2], Q[3]);
}

__global__ __launch_bounds__(256) void scan_bounds_kernel(
    const float* __restrict__ Pb, const float* __restrict__ Qb, float* __restrict__ Hi)
{
  const int i = blockIdx.x * 256 + threadIdx.x;
  const int b = i >> 15;
  const int r = i & 32767;
  float h = 0.f;
#pragma unroll
  for (int c = 0; c < NC; ++c) {
    const size_t o = ((size_t)(b * NC + c) << 15) + r;
    Hi[o] = h;
    h = Pb[o] * h + Qb[o];
  }
}

__global__ __launch_bounds__(256) void scan_final_kernel(
    const float* __restrict__ delta, const float* __restrict__ xc,
    const float* __restrict__ xdbl, const float* __restrict__ xz,
    const float* __restrict__ A_log, const float* __restrict__ Dp,
    const float* __restrict__ Hi, uint16_t* __restrict__ yb)
{
  const int q = threadIdx.x & 3;
  const int d_idx = threadIdx.x >> 2;
  const int c = blockIdx.x;
  const int d = blockIdx.y * 64 + d_idx;
  const int b = blockIdx.z;
  float Arow[4];
#pragma unroll
  for (int n = 0; n < 4; ++n)
    Arow[n] = -expf(A_log[d * 16 + q * 4 + n]);
  const float dpd = Dp[d];
  const size_t o = ((size_t)(b * NC + c) * DIN + d) * 16 + q * 4;
  const float4 Hv = *(const float4*)(Hi + o);
  float h[4] = {Hv.x, Hv.y, Hv.z, Hv.w};
  const int l0 = c * CL;
#pragma unroll 2
  for (int li = 0; li < CL; ++li) {
    const int m = b * LSEQ + l0 + li;
    const float de = delta[(size_t)m * DIN + d];
    const float xv = xc[(size_t)m * DIN + d];
    const float dx = de * xv;
    const float4 Bv = *(const float4*)(xdbl + (size_t)m * 128 + 64 + q * 4);
    const float4 Cv = *(const float4*)(xdbl + (size_t)m * 128 + 80 + q * 4);
    const float bv[4] = {Bv.x, Bv.y, Bv.z, Bv.w};
    const float cv[4] = {Cv.x, Cv.y, Cv.z, Cv.w};
    float yp = 0.f;
#pragma unroll
    for (int n = 0; n < 4; ++n) {
      const float a = __expf(de * Arow[n]);
      h[n] = a * h[n] + dx * bv[n];
      yp += h[n] * cv[n];
    }
    yp += __shfl_xor(yp, 1);
    yp += __shfl_xor(yp, 2);
    if (q == 0) {
      const float z = xz[(size_t)m * 4096 + 2048 + d];
      const float sil = z / (1.f + __expf(-z));
      yb[(size_t)m * DIN + d] = f2bf((yp + xv * dpd) * sil);
    }
  }
}

__global__ __launch_bounds__(256) void pool_kernel(
    const float* __restrict__ h2, float* __restrict__ pooled) {
  const int b = blockIdx.x, t = threadIdx.x;
  const float4* base = (const float4*)(h2 + (size_t)b * LSEQ * DMODEL);
  float sx = 0, sy = 0, sz = 0, sw = 0;
  for (int l = 0; l < LSEQ; ++l) {
    const float4 v = base[l * (DMODEL / 4) + t];
    sx += v.x; sy += v.y; sz += v.z; sw += v.w;
  }
  const float inv = 1.f / LSEQ;
  ((float4*)pooled)[b * (DMODEL / 4) + t] = make_float4(sx * inv, sy * inv, sz * inv, sw * inv);
}

__global__ __launch_bounds__(64) void cls_kernel(
    const float* __restrict__ pooled, const float* __restrict__ w, float* __restrict__ out) {
  const int o = blockIdx.x;
  const int b = o >> 7, c = o & 127;
  const int lane = threadIdx.x;
  const float* p = pooled + b * 1024;
  const float* wr = w + c * 1024;
  float s = 0.f;
  for (int k = lane; k < 1024; k += 64) s += p[k] * wr[k];
#pragma unroll
  for (int off = 32; off > 0; off >>= 1) s += __shfl_down(s, off);
  if (lane == 0) out[o] = s;
}

extern "C" void kernel_launch(void* const* d_in, const int* in_sizes, int n_in,
                              void* d_out, int out_size, void* d_ws, size_t ws_size,
                              hipStream_t stream) {
  const int*   tokens    = (const int*)d_in[0];
  const float* embedding = (const float*)d_in[1];
  const float* in_proj_w = (const float*)d_in[2];
  const float* conv_w    = (const float*)d_in[3];
  const float* conv_b    = (const float*)d_in[4];
  const float* x_proj_w  = (const float*)d_in[5];
  const float* dt_proj_w = (const float*)d_in[6];
  const float* dt_proj_b = (const float*)d_in[7];
  const float* A_log     = (const float*)d_in[8];
  const float* D_param   = (const float*)d_in[9];
  const float* out_prj_w = (const float*)d_in[10];
  const float* recon_w   = (const float*)d_in[11];
  const float* cls_w     = (const float*)d_in[12];

  char* ws = (char*)d_ws;
  const size_t MB = 1024 * 1024;
  uint16_t* h_bf   = (uint16_t*)(ws + 0);        // 4MB
  uint16_t* w_in   = (uint16_t*)(ws + 4 * MB);   // 8MB  [dead after GEMM1]
  float*    xz     = (float*)(ws + 12 * MB);     // 32MB [dead after scan C]
  float*    xc_f   = (float*)(ws + 44 * MB);     // 16MB
  uint16_t* xc_b   = (uint16_t*)(ws + 60 * MB);  // 8MB  [dead after x_proj GEMM]
  uint16_t* wx_bf  = (uint16_t*)(ws + 68 * MB);  // 0.5MB
  float*    xdbl   = (float*)(ws + 69 * MB);     // 1MB
  uint16_t* dt_bf  = (uint16_t*)(ws + 70 * MB);  // 0.25MB
  uint16_t* wdt_bf = (uint16_t*)(ws + 71 * MB);  // 0.25MB
  float*    delta  = (float*)(ws + 72 * MB);     // 16MB (also split-K scratch)
  uint16_t* y_bf   = (uint16_t*)(ws + 88 * MB);  // 8MB
  uint16_t* h2_bf  = (uint16_t*)(ws + 96 * MB);  // 4MB
  float*    pooled = (float*)(ws + 100 * MB);    // 16KB
  // aliases (lifetime-disjoint)
  uint16_t* wout_bf = h_bf;
  float*    h2_f    = (float*)w_in;
  uint16_t* wrec_bf = (uint16_t*)xz;
  float*    kscr    = delta;
  float*    Pbuf    = (float*)(ws + 60 * MB);
  float*    Qbuf    = (float*)(ws + 64 * MB);
  float*    Hinit   = (float*)(ws + 4 * MB);

  const int RECON = MROWS * NV;

  embed_kernel<<<dim3(MROWS), dim3(256), 0, stream>>>(tokens, embedding, h_bf);
  cvt_bf16_kernel<<<dim3(4096), dim3(256), 0, stream>>>(in_proj_w, w_in, 4096 * 1024 / 4);
  // in_proj: 2048 x 4096, K=1024 -> 128 blocks
  gemm256_bf16_kernel<<<dim3(128), dim3(512), 0, stream>>>(h_bf, w_in, xz, MROWS, 4096, 1024);
  cvt_bf16_kernel<<<dim3(2048), dim3(256), 0, stream>>>(out_prj_w, wout_bf, 1024 * 2048 / 4);
  cvt_bf16_kernel<<<dim3(128), dim3(256), 0, stream>>>(dt_proj_w, wdt_bf, 2048 * 64 / 4);
  cvt_pad_kernel<<<dim3(256), dim3(256), 0, stream>>>(x_proj_w, wx_bf, 96, 512);
  conv_silu_kernel<<<dim3(16384), dim3(256), 0, stream>>>(xz, conv_w, conv_b, xc_f, xc_b);
  gemm_bf16_kernel<<<dim3(1, 16, 4), dim3(256), 0, stream>>>(xc_b, wx_bf, kscr, MROWS, 128, 2048, 512);
  reduce_slices_kernel<<<dim3(1024), dim3(256), 0, stream>>>(kscr, xdbl, MROWS * 128, 4);
  dt_extract_kernel<<<dim3(512), dim3(256), 0, stream>>>(xdbl, dt_bf);
  gemm_bf16_kernel<<<dim3(16, 16, 1), dim3(256), 0, stream>>>(dt_bf, wdt_bf, delta, MROWS, DIN, 64, 64);
  softplus_kernel<<<dim3(16384), dim3(256), 0, stream>>>(delta, dt_proj_b);
  scan_partial_kernel<<<dim3(NC, 32, 4), dim3(256), 0, stream>>>(delta, xc_f, xdbl, A_log, Pbuf, Qbuf);
  scan_bounds_kernel<<<dim3(512), dim3(256), 0, stream>>>(Pbuf, Qbuf, Hinit);
  scan_final_kernel<<<dim3(NC, 32, 4), dim3(256), 0, stream>>>(delta, xc_f, xdbl, xz, A_log, D_param, Hinit, y_bf);
  cvt_bf16_kernel<<<dim3(16384), dim3(256), 0, stream>>>(recon_w, wrec_bf, NV * 1024 / 4);
  // out_proj: 2048 x 1024, K=2048 -> 32 blocks, fp32 direct (no split-K)
  gemm256_bf16_kernel<<<dim3(32), dim3(512), 0, stream>>>(y_bf, wout_bf, h2_f, MROWS, 1024, 2048);
  cvt_bf16_kernel<<<dim3(2048), dim3(256), 0, stream>>>(h2_f, h2_bf, MROWS * 1024 / 4);
  // recon: 2048 x 16384, K=1024 -> 512 blocks
  gemm256_bf16_kernel<<<dim3(512), dim3(512), 0, stream>>>(h2_bf, wrec_bf, (float*)d_out, MROWS, NV, 1024);
  pool_kernel<<<dim3(4), dim3(256), 0, stream>>>(h2_f, pooled);
  cls_kernel<<<dim3(512), dim3(64), 0, stream>>>(pooled, cls_w, (float*)d_out + RECON);
}

// Round 4
// 374.973 us; speedup vs baseline: 1.7395x; 1.0210x over previous
//
#include <hip/hip_runtime.h>
#include <hip/hip_bf16.h>
#include <stdint.h>

#define DIN    2048
#define MROWS  2048
#define LSEQ   512
#define NV     16384
#define DMODEL 1024
#define NC     8      // scan chunks
#define CL     64     // steps per chunk

typedef __attribute__((ext_vector_type(8))) short bf16x8;
typedef __attribute__((ext_vector_type(4))) float f32x4;

__device__ __forceinline__ uint16_t f2bf(float f) {
  uint32_t u = __builtin_bit_cast(uint32_t, f);
  u += 0x7fffu + ((u >> 16) & 1u);
  return (uint16_t)(u >> 16);
}
__device__ __forceinline__ float bf2f(uint16_t u) {
  return __builtin_bit_cast(float, (uint32_t)u << 16);
}

__device__ __forceinline__ void gld_lds16(const uint16_t* g, uint16_t* l) {
  __builtin_amdgcn_global_load_lds(
      (const __attribute__((address_space(1))) void*)g,
      (__attribute__((address_space(3))) void*)l,
      16, 0, 0);
}

// ---------------------------------------------------------------------------
// 256x256 tile, BK=32, 8 waves (2M x 4N), 4-slot LDS (128KB) counted-vmcnt
// ring + 2-phase per K-tile interleave (T3): each phase = {ds_read subtile,
// stage half, barrier, lgkmcnt(0), setprio MFMA x16, barrier}. XOR-swizzled
// LDS (0 bank conflicts, verified r3), XCD-aware block swizzle.
// C = A(M,K)*B(N,K)^T. Cf (fp32) and/or Cbf (bf16) outputs, either nullable.
// Requires M%256==0, N%256==0, K%32==0, K>=128, grid=(M/256)*(N/256), %8==0.
// ---------------------------------------------------------------------------
__global__ __launch_bounds__(512, 2) void gemm256_bf16_kernel(
    const uint16_t* __restrict__ A, const uint16_t* __restrict__ B,
    float* __restrict__ Cf, uint16_t* __restrict__ Cbf, int M, int N, int K)
{
  __shared__ uint16_t lds[4 * 16384];   // 4 slots x (A 16KB | B 16KB)
  const int tid = threadIdx.x;
  const int w   = tid >> 6;
  const int l   = tid & 63;

  const int nwg = gridDim.x;
  const int cpx = nwg >> 3;
  const int swz = (blockIdx.x & 7) * cpx + (blockIdx.x >> 3);
  const int nmy = M >> 8;
  const int bm  = (swz % nmy) << 8;
  const int bn  = (swz / nmy) << 8;

  const int fr = l & 15;
  const int fg = l >> 4;
  const int wr = w >> 2;     // 0..1
  const int wc = w & 3;      // 0..3

  // staging: source pre-swizzled, LDS dest linear (rule #21 pair)
  const int srow = l >> 2;
  const int kof  = (((l & 3) ^ ((l >> 3) & 3)) << 3);
  const int ar0  = (w * 2 + 0) * 16 + srow;
  const int ar1  = (w * 2 + 1) * 16 + srow;
  const uint16_t* Ag0 = A + (size_t)(bm + ar0) * K + kof;
  const uint16_t* Ag1 = A + (size_t)(bm + ar1) * K + kof;
  const uint16_t* Bg0 = B + (size_t)(bn + ar0) * K + kof;
  const uint16_t* Bg1 = B + (size_t)(bn + ar1) * K + kof;
  const int lA0 = (w * 2 + 0) * 512;
  const int lA1 = (w * 2 + 1) * 512;
  const int lB0 = 8192 + (w * 2 + 0) * 512;
  const int lB1 = 8192 + (w * 2 + 1) * 512;

  // swizzled ds_read offsets
  const int axr  = ((fg ^ ((fr >> 1) & 3)) << 3);
  const int aoff = (wr * 128 + fr) * 32 + axr;          // + mi*512
  const int boff = 8192 + (wc * 64 + fr) * 32 + axr;    // + ni*512

  f32x4 acc[8][4] = {};
  const int NT = K >> 5;

  auto stage_all = [&](int t) {
    const int sb = (t & 3) << 14;
    const int k0 = t << 5;
    gld_lds16(Ag0 + k0, lds + sb + lA0);
    gld_lds16(Ag1 + k0, lds + sb + lA1);
    gld_lds16(Bg0 + k0, lds + sb + lB0);
    gld_lds16(Bg1 + k0, lds + sb + lB1);
  };
  auto compute_full = [&](int sb) {    // tail iterations (no prefetch)
    bf16x8 af[8], bfr[4];
#pragma unroll
    for (int mi = 0; mi < 8; ++mi)
      af[mi] = *(const bf16x8*)(lds + sb + aoff + mi * 512);
#pragma unroll
    for (int ni = 0; ni < 4; ++ni)
      bfr[ni] = *(const bf16x8*)(lds + sb + boff + ni * 512);
    __builtin_amdgcn_s_setprio(1);
#pragma unroll
    for (int mi = 0; mi < 8; ++mi)
#pragma unroll
      for (int ni = 0; ni < 4; ++ni)
        acc[mi][ni] = __builtin_amdgcn_mfma_f32_16x16x32_bf16(af[mi], bfr[ni], acc[mi][ni], 0, 0, 0);
    __builtin_amdgcn_s_setprio(0);
  };

  // prologue: tiles 0..2 in flight (12 loads), wait tile 0 (leave 8)
  stage_all(0); stage_all(1); stage_all(2);
  asm volatile("s_waitcnt vmcnt(8)" ::: "memory");
  __builtin_amdgcn_s_barrier();

  for (int t = 0; t < NT - 3; ++t) {
    const int sb = (t & 3) << 14;
    const int st = ((t + 3) & 3) << 14;
    const int k0 = (t + 3) << 5;
    bf16x8 af[8], bfr[4];
    // ---- phase 1: A frags + B frags 0-1; stage A half of tile t+3 ----
#pragma unroll
    for (int mi = 0; mi < 8; ++mi)
      af[mi] = *(const bf16x8*)(lds + sb + aoff + mi * 512);
    bfr[0] = *(const bf16x8*)(lds + sb + boff + 0 * 512);
    bfr[1] = *(const bf16x8*)(lds + sb + boff + 1 * 512);
    gld_lds16(Ag0 + k0, lds + st + lA0);
    gld_lds16(Ag1 + k0, lds + st + lA1);
    __builtin_amdgcn_s_barrier();
    asm volatile("s_waitcnt lgkmcnt(0)" ::: "memory");
    __builtin_amdgcn_sched_barrier(0);
    __builtin_amdgcn_s_setprio(1);
#pragma unroll
    for (int mi = 0; mi < 8; ++mi)
#pragma unroll
      for (int ni = 0; ni < 2; ++ni)
        acc[mi][ni] = __builtin_amdgcn_mfma_f32_16x16x32_bf16(af[mi], bfr[ni], acc[mi][ni], 0, 0, 0);
    __builtin_amdgcn_s_setprio(0);
    __builtin_amdgcn_s_barrier();
    // ---- phase 2: B frags 2-3; stage B half of tile t+3 ----
    bfr[2] = *(const bf16x8*)(lds + sb + boff + 2 * 512);
    bfr[3] = *(const bf16x8*)(lds + sb + boff + 3 * 512);
    gld_lds16(Bg0 + k0, lds + st + lB0);
    gld_lds16(Bg1 + k0, lds + st + lB1);
    __builtin_amdgcn_s_barrier();
    asm volatile("s_waitcnt lgkmcnt(0)" ::: "memory");
    __builtin_amdgcn_sched_barrier(0);
    __builtin_amdgcn_s_setprio(1);
#pragma unroll
    for (int mi = 0; mi < 8; ++mi)
#pragma unroll
      for (int ni = 2; ni < 4; ++ni)
        acc[mi][ni] = __builtin_amdgcn_mfma_f32_16x16x32_bf16(af[mi], bfr[ni], acc[mi][ni], 0, 0, 0);
    __builtin_amdgcn_s_setprio(0);
    asm volatile("s_waitcnt vmcnt(8)" ::: "memory");   // tile t+1 landed
    __builtin_amdgcn_s_barrier();
  }
  compute_full(((NT - 3) & 3) << 14);
  asm volatile("s_waitcnt vmcnt(4)" ::: "memory");
  __builtin_amdgcn_s_barrier();
  compute_full(((NT - 2) & 3) << 14);
  asm volatile("s_waitcnt vmcnt(0)" ::: "memory");
  __builtin_amdgcn_s_barrier();
  compute_full(((NT - 1) & 3) << 14);

#pragma unroll
  for (int mi = 0; mi < 8; ++mi) {
    const int r0 = bm + wr * 128 + mi * 16 + fg * 4;
#pragma unroll
    for (int ni = 0; ni < 4; ++ni) {
      const int c0 = bn + wc * 64 + ni * 16 + fr;
#pragma unroll
      for (int r = 0; r < 4; ++r) {
        const float v = acc[mi][ni][r];
        if (Cf)  Cf[(size_t)(r0 + r) * N + c0] = v;
        if (Cbf) Cbf[(size_t)(r0 + r) * N + c0] = f2bf(v);
      }
    }
  }
}

// ---- 128x128 kernel (small GEMMs); optional fused bias+softplus epilogue ----
__global__ __launch_bounds__(256) void gemm_bf16_kernel(
    const uint16_t* __restrict__ A, const uint16_t* __restrict__ B,
    float* __restrict__ C, int M, int N, int K, int kchunk,
    const float* __restrict__ bias)
{
  __shared__ uint16_t As[128 * 32];
  __shared__ uint16_t Bs[128 * 32];
  const int tid  = threadIdx.x;
  const int wid  = tid >> 6;
  const int lane = tid & 63;
  const int bm = blockIdx.y * 128;
  const int bn = blockIdx.x * 128;
  const int k_beg = blockIdx.z * kchunk;
  float* Cout = C + (size_t)blockIdx.z * M * N;

  const int fr = lane & 15;
  const int fg = lane >> 4;
  const int wm = (wid >> 1) * 64;
  const int wn = (wid & 1) * 64;

  const int srow = wid * 32 + (lane >> 2);
  const int skof = (lane & 3) * 8;
  const uint16_t* Ag = A + (size_t)(bm + srow) * K + skof;
  const uint16_t* Bg = B + (size_t)(bn + srow) * K + skof;
  uint16_t* Al = As + wid * 1024;
  uint16_t* Bl = Bs + wid * 1024;

  f32x4 acc[4][4] = {};

  for (int k0 = 0; k0 < kchunk; k0 += 32) {
    const int kk = k_beg + k0;
    gld_lds16(Ag + kk, Al);
    gld_lds16(Ag + (size_t)16 * K + kk, Al + 512);
    gld_lds16(Bg + kk, Bl);
    gld_lds16(Bg + (size_t)16 * K + kk, Bl + 512);
    asm volatile("s_waitcnt vmcnt(0)" ::: "memory");
    __syncthreads();
    bf16x8 af[4], bfr[4];
#pragma unroll
    for (int i = 0; i < 4; ++i)
      af[i] = *(const bf16x8*)(As + (wm + i * 16 + fr) * 32 + fg * 8);
#pragma unroll
    for (int j = 0; j < 4; ++j)
      bfr[j] = *(const bf16x8*)(Bs + (wn + j * 16 + fr) * 32 + fg * 8);
#pragma unroll
    for (int i = 0; i < 4; ++i)
#pragma unroll
      for (int j = 0; j < 4; ++j)
        acc[i][j] = __builtin_amdgcn_mfma_f32_16x16x32_bf16(af[i], bfr[j], acc[i][j], 0, 0, 0);
    __syncthreads();
  }

#pragma unroll
  for (int i = 0; i < 4; ++i) {
    const int r0 = bm + wm + i * 16 + fg * 4;
#pragma unroll
    for (int j = 0; j < 4; ++j) {
      const int c0 = bn + wn + j * 16 + fr;
      const float bv = bias ? bias[c0] : 0.f;
#pragma unroll
      for (int r = 0; r < 4; ++r) {
        float v = acc[i][j][r];
        if (bias) {
          const float u = v + bv;
          v = (u > 20.f) ? u : log1pf(__expf(u));
        }
        Cout[(size_t)(r0 + r) * N + c0] = v;
      }
    }
  }
}

// x_proj split-K reduce (4 slices) + dt slice -> bf16
__global__ __launch_bounds__(256) void reduce4_dt_kernel(
    const float* __restrict__ in, float* __restrict__ xdbl, uint16_t* __restrict__ dtb) {
  const int i = blockIdx.x * 256 + threadIdx.x;   // 262144 = 2048*128
  const float s = in[i] + in[i + 262144] + in[i + 2 * 262144] + in[i + 3 * 262144];
  xdbl[i] = s;
  const int c = i & 127;
  if (c < 64) dtb[(i >> 7) * 64 + c] = f2bf(s);
}

// out_proj split-K reduce (2 slices) -> bf16 h2
__global__ __launch_bounds__(256) void reduce2_bf16_kernel(
    const float* __restrict__ in, uint16_t* __restrict__ outb, int n) {
  const int i = blockIdx.x * 256 + threadIdx.x;
  if (i >= n) return;
  outb[i] = f2bf(in[i] + in[i + (size_t)n]);
}

__global__ __launch_bounds__(256) void embed_kernel(
    const int* __restrict__ tok, const float* __restrict__ emb, uint16_t* __restrict__ out) {
  const int m = blockIdx.x;
  const int t = tok[m];
  const float4 v = ((const float4*)(emb + (size_t)t * DMODEL))[threadIdx.x];
  ((ushort4*)(out + (size_t)m * DMODEL))[threadIdx.x] =
      make_ushort4(f2bf(v.x), f2bf(v.y), f2bf(v.z), f2bf(v.w));
}

__global__ __launch_bounds__(256) void cvt_bf16_kernel(
    const float* __restrict__ in, uint16_t* __restrict__ out, int n4) {
  const int i = blockIdx.x * 256 + threadIdx.x;
  if (i >= n4) return;
  const float4 v = ((const float4*)in)[i];
  ((ushort4*)out)[i] = make_ushort4(f2bf(v.x), f2bf(v.y), f2bf(v.z), f2bf(v.w));
}

__global__ __launch_bounds__(256) void cvt_pad_kernel(
    const float* __restrict__ in, uint16_t* __restrict__ out, int rows_in, int cols4) {
  const int i = blockIdx.x * 256 + threadIdx.x;
  const int r = i / cols4, c = i % cols4;
  ushort4 o = make_ushort4(0, 0, 0, 0);
  if (r < rows_in) {
    const float4 v = ((const float4*)in)[(size_t)r * cols4 + c];
    o = make_ushort4(f2bf(v.x), f2bf(v.y), f2bf(v.z), f2bf(v.w));
  }
  ((ushort4*)out)[i] = o;
}

__global__ __launch_bounds__(256) void conv_silu_kernel(
    const float* __restrict__ xz, const float* __restrict__ cw, const float* __restrict__ cb,
    float* __restrict__ xc, uint16_t* __restrict__ xcb)
{
  const int idx = blockIdx.x * 256 + threadIdx.x;
  const int d = idx & (DIN - 1);
  const int m = idx >> 11;
  const int l = m & (LSEQ - 1);
  float acc = cb[d];
#pragma unroll
  for (int j = 0; j < 4; ++j) {
    const int lj = l - 3 + j;
    if (lj >= 0) acc += cw[d * 4 + j] * xz[(size_t)(m - 3 + j) * 4096 + d];
  }
  const float r = acc / (1.f + __expf(-acc));
  xc[idx] = r;
  xcb[idx] = f2bf(r);
}

__global__ __launch_bounds__(256) void scan_partial_kernel(
    const float* __restrict__ delta, const float* __restrict__ xc,
    const float* __restrict__ xdbl, const float* __restrict__ A_log,
    float* __restrict__ Pb, float* __restrict__ Qb)
{
  const int q = threadIdx.x & 3;
  const int d_idx = threadIdx.x >> 2;
  const int c = blockIdx.x;
  const int d = blockIdx.y * 64 + d_idx;
  const int b = blockIdx.z;
  float Arow[4];
#pragma unroll
  for (int n = 0; n < 4; ++n)
    Arow[n] = -expf(A_log[d * 16 + q * 4 + n]);
  float P[4] = {1.f, 1.f, 1.f, 1.f};
  float Q[4] = {0.f, 0.f, 0.f, 0.f};
  const int l0 = c * CL;
#pragma unroll 4
  for (int li = 0; li < CL; ++li) {
    const int m = b * LSEQ + l0 + li;
    const float de = delta[(size_t)m * DIN + d];
    const float xv = xc[(size_t)m * DIN + d];
    const float dx = de * xv;
    const float4 Bv = *(const float4*)(xdbl + (size_t)m * 128 + 64 + q * 4);
    const float bv[4] = {Bv.x, Bv.y, Bv.z, Bv.w};
#pragma unroll
    for (int n = 0; n < 4; ++n) {
      const float a = __expf(de * Arow[n]);
      P[n] *= a;
      Q[n] = a * Q[n] + dx * bv[n];
    }
  }
  const size_t o = ((size_t)(b * NC + c) * DIN + d) * 16 + q * 4;
  *(float4*)(Pb + o) = make_float4(P[0], P[1], P[2], P[3]);
  *(float4*)(Qb + o) = make_float4(Q[0], Q[1], Q[2], Q[3]);
}

__global__ __launch_bounds__(256) void scan_bounds_kernel(
    const float* __restrict__ Pb, const float* __restrict__ Qb, float* __restrict__ Hi)
{
  const int i = blockIdx.x * 256 + threadIdx.x;
  const int b = i >> 15;
  const int r = i & 32767;
  float h = 0.f;
#pragma unroll
  for (int c = 0; c < NC; ++c) {
    const size_t o = ((size_t)(b * NC + c) << 15) + r;
    Hi[o] = h;
    h = Pb[o] * h + Qb[o];
  }
}

__global__ __launch_bounds__(256) void scan_final_kernel(
    const float* __restrict__ delta, const float* __restrict__ xc,
    const float* __restrict__ xdbl, const float* __restrict__ xz,
    const float* __restrict__ A_log, const float* __restrict__ Dp,
    const float* __restrict__ Hi, uint16_t* __restrict__ yb)
{
  const int q = threadIdx.x & 3;
  const int d_idx = threadIdx.x >> 2;
  const int c = blockIdx.x;
  const int d = blockIdx.y * 64 + d_idx;
  const int b = blockIdx.z;
  float Arow[4];
#pragma unroll
  for (int n = 0; n < 4; ++n)
    Arow[n] = -expf(A_log[d * 16 + q * 4 + n]);
  const float dpd = Dp[d];
  const size_t o = ((size_t)(b * NC + c) * DIN + d) * 16 + q * 4;
  const float4 Hv = *(const float4*)(Hi + o);
  float h[4] = {Hv.x, Hv.y, Hv.z, Hv.w};
  const int l0 = c * CL;
#pragma unroll 2
  for (int li = 0; li < CL; ++li) {
    const int m = b * LSEQ + l0 + li;
    const float de = delta[(size_t)m * DIN + d];
    const float xv = xc[(size_t)m * DIN + d];
    const float dx = de * xv;
    const float4 Bv = *(const float4*)(xdbl + (size_t)m * 128 + 64 + q * 4);
    const float4 Cv = *(const float4*)(xdbl + (size_t)m * 128 + 80 + q * 4);
    const float bv[4] = {Bv.x, Bv.y, Bv.z, Bv.w};
    const float cv[4] = {Cv.x, Cv.y, Cv.z, Cv.w};
    float yp = 0.f;
#pragma unroll
    for (int n = 0; n < 4; ++n) {
      const float a = __expf(de * Arow[n]);
      h[n] = a * h[n] + dx * bv[n];
      yp += h[n] * cv[n];
    }
    yp += __shfl_xor(yp, 1);
    yp += __shfl_xor(yp, 2);
    if (q == 0) {
      const float z = xz[(size_t)m * 4096 + 2048 + d];
      const float sil = z / (1.f + __expf(-z));
      yb[(size_t)m * DIN + d] = f2bf((yp + xv * dpd) * sil);
    }
  }
}

// mean-pool partials: block (b,s) sums 32 L-rows of bf16 h2
__global__ __launch_bounds__(256) void pool1_kernel(
    const uint16_t* __restrict__ h2b, float* __restrict__ part) {
  const int b = blockIdx.x >> 4, s = blockIdx.x & 15;
  const int c = threadIdx.x * 4;
  const uint16_t* base = h2b + ((size_t)(b * LSEQ + s * 32)) * DMODEL + c;
  float a0 = 0, a1 = 0, a2 = 0, a3 = 0;
  for (int l = 0; l < 32; ++l) {
    const ushort4 v = *(const ushort4*)(base + (size_t)l * DMODEL);
    a0 += bf2f(v.x); a1 += bf2f(v.y); a2 += bf2f(v.z); a3 += bf2f(v.w);
  }
  *(float4*)(part + (size_t)blockIdx.x * DMODEL + c) = make_float4(a0, a1, a2, a3);
}

// final pool reduce + CLS head, one block per batch
__global__ __launch_bounds__(256) void pool2_cls_kernel(
    const float* __restrict__ part, const float* __restrict__ w, float* __restrict__ out) {
  __shared__ float pl[DMODEL];
  const int b = blockIdx.x, t = threadIdx.x;
  float4 s = make_float4(0, 0, 0, 0);
  for (int k = 0; k < 16; ++k) {
    const float4 v = *(const float4*)(part + ((size_t)(b * 16 + k)) * DMODEL + t * 4);
    s.x += v.x; s.y += v.y; s.z += v.z; s.w += v.w;
  }
  const float inv = 1.f / (float)LSEQ;
  pl[t * 4 + 0] = s.x * inv; pl[t * 4 + 1] = s.y * inv;
  pl[t * 4 + 2] = s.z * inv; pl[t * 4 + 3] = s.w * inv;
  __syncthreads();
  if (t < 128) {
    const float* wr = w + (size_t)t * DMODEL;
    float acc = 0.f;
    for (int k = 0; k < DMODEL; ++k) acc += pl[k] * wr[k];
    out[b * 128 + t] = acc;
  }
}

extern "C" void kernel_launch(void* const* d_in, const int* in_sizes, int n_in,
                              void* d_out, int out_size, void* d_ws, size_t ws_size,
                              hipStream_t stream) {
  const int*   tokens    = (const int*)d_in[0];
  const float* embedding = (const float*)d_in[1];
  const float* in_proj_w = (const float*)d_in[2];
  const float* conv_w    = (const float*)d_in[3];
  const float* conv_b    = (const float*)d_in[4];
  const float* x_proj_w  = (const float*)d_in[5];
  const float* dt_proj_w = (const float*)d_in[6];
  const float* dt_proj_b = (const float*)d_in[7];
  const float* A_log     = (const float*)d_in[8];
  const float* D_param   = (const float*)d_in[9];
  const float* out_prj_w = (const float*)d_in[10];
  const float* recon_w   = (const float*)d_in[11];
  const float* cls_w     = (const float*)d_in[12];

  char* ws = (char*)d_ws;
  const size_t MB = 1024 * 1024;
  uint16_t* h_bf   = (uint16_t*)(ws + 0);        // 4MB
  uint16_t* w_in   = (uint16_t*)(ws + 4 * MB);   // 8MB  [dead after GEMM1]
  float*    xz     = (float*)(ws + 12 * MB);     // 32MB [dead after scan C]
  float*    xc_f   = (float*)(ws + 44 * MB);     // 16MB
  uint16_t* xc_b   = (uint16_t*)(ws + 60 * MB);  // 8MB  [dead after x_proj GEMM]
  uint16_t* wx_bf  = (uint16_t*)(ws + 68 * MB);  // 0.5MB
  float*    xdbl   = (float*)(ws + 69 * MB);     // 1MB
  uint16_t* dt_bf  = (uint16_t*)(ws + 70 * MB);  // 0.25MB
  uint16_t* wdt_bf = (uint16_t*)(ws + 71 * MB);  // 0.25MB
  float*    delta  = (float*)(ws + 72 * MB);     // 16MB (also split-K scratch)
  uint16_t* y_bf   = (uint16_t*)(ws + 88 * MB);  // 8MB
  uint16_t* h2_bf  = (uint16_t*)(ws + 96 * MB);  // 4MB
  float*    part   = (float*)(ws + 100 * MB);    // 256KB pool partials
  // aliases (lifetime-disjoint)
  uint16_t* wout_bf = h_bf;
  uint16_t* wrec_bf = (uint16_t*)xz;
  float*    kscr    = delta;
  float*    Pbuf    = (float*)(ws + 60 * MB);
  float*    Qbuf    = (float*)(ws + 64 * MB);
  float*    Hinit   = (float*)(ws + 4 * MB);

  const int RECON = MROWS * NV;

  embed_kernel<<<dim3(MROWS), dim3(256), 0, stream>>>(tokens, embedding, h_bf);
  cvt_bf16_kernel<<<dim3(4096), dim3(256), 0, stream>>>(in_proj_w, w_in, 4096 * 1024 / 4);
  // in_proj: 2048 x 4096, K=1024 -> 128 blocks
  gemm256_bf16_kernel<<<dim3(128), dim3(512), 0, stream>>>(h_bf, w_in, xz, nullptr, MROWS, 4096, 1024);
  cvt_bf16_kernel<<<dim3(2048), dim3(256), 0, stream>>>(out_prj_w, wout_bf, 1024 * 2048 / 4);
  cvt_bf16_kernel<<<dim3(128), dim3(256), 0, stream>>>(dt_proj_w, wdt_bf, 2048 * 64 / 4);
  cvt_pad_kernel<<<dim3(256), dim3(256), 0, stream>>>(x_proj_w, wx_bf, 96, 512);
  conv_silu_kernel<<<dim3(16384), dim3(256), 0, stream>>>(xz, conv_w, conv_b, xc_f, xc_b);
  // x_dbl = x @ x_proj_w^T (split-K x4)
  gemm_bf16_kernel<<<dim3(1, 16, 4), dim3(256), 0, stream>>>(xc_b, wx_bf, kscr, MROWS, 128, 2048, 512, nullptr);
  reduce4_dt_kernel<<<dim3(1024), dim3(256), 0, stream>>>(kscr, xdbl, dt_bf);
  // delta = softplus(dt @ dt_proj_w^T + b)  (fused epilogue)
  gemm_bf16_kernel<<<dim3(16, 16, 1), dim3(256), 0, stream>>>(dt_bf, wdt_bf, delta, MROWS, DIN, 64, 64, dt_proj_b);
  scan_partial_kernel<<<dim3(NC, 32, 4), dim3(256), 0, stream>>>(delta, xc_f, xdbl, A_log, Pbuf, Qbuf);
  scan_bounds_kernel<<<dim3(512), dim3(256), 0, stream>>>(Pbuf, Qbuf, Hinit);
  scan_final_kernel<<<dim3(NC, 32, 4), dim3(256), 0, stream>>>(delta, xc_f, xdbl, xz, A_log, D_param, Hinit, y_bf);
  cvt_bf16_kernel<<<dim3(16384), dim3(256), 0, stream>>>(recon_w, wrec_bf, NV * 1024 / 4);
  // out_proj: split-K x2, reduce straight to bf16 h2
  gemm_bf16_kernel<<<dim3(8, 16, 2), dim3(256), 0, stream>>>(y_bf, wout_bf, kscr, MROWS, 1024, 2048, 1024, nullptr);
  reduce2_bf16_kernel<<<dim3(8192), dim3(256), 0, stream>>>(kscr, h2_bf, MROWS * 1024);
  // recon: 2048 x 16384, K=1024 -> 512 blocks
  gemm256_bf16_kernel<<<dim3(512), dim3(512), 0, stream>>>(h2_bf, wrec_bf, (float*)d_out, nullptr, MROWS, NV, 1024);
  pool1_kernel<<<dim3(64), dim3(256), 0, stream>>>(h2_bf, part);
  pool2_cls_kernel<<<dim3(4), dim3(256), 0, stream>>>(part, cls_w, (float*)d_out + RECON);
}